// Round 8
// baseline (172.737 us; speedup 1.0000x reference)
//
#include <hip/hip_runtime.h>

// Output: (B=512, H=128, W=128, C=5) fp32.
// ch0 = stamp[h,w]; ch1 = scatter-add (fused via LDS patch); ch2 = x[b,h>>2];
// ch3 = |x[b,h>>2]-x[b,w>>2]| / (max-min); ch4 = bar (col 17+3i is bar i, h<bh[i]).
// Block = (b, part): 1024 pixels = rows [part*8, part*8+8) of image b.
// compute -> stage(LDS) -> barrier -> patch ch1 (LDS atomics) -> barrier ->
// 5 back-to-back nontemporal dwordx4 stores (wave = contiguous 1024B). No
// post-store barrier: waves retire immediately after issuing stores.

typedef float f32x4 __attribute__((ext_vector_type(4)));   // native vec for nontemporal

__global__ __launch_bounds__(256) void di_main(const float* __restrict__ inputs,
                                               const float* __restrict__ stamp,
                                               const int* __restrict__ coords,
                                               float* __restrict__ out) {
    const int blk = blockIdx.x;     // 8192 blocks: 512 b x 16 parts
    const int b = blk >> 4;
    const int part = blk & 15;
    const int tid = threadIdx.x;
    const int lane = tid & 63;

    __shared__ float buf[256 * 20];   // 20 KB staging -> 8 blocks/CU

    // pixel span: lp..lp+3 (one row-quarter of 4 px)
    const int lp = part * 1024 + tid * 4;
    const int h = lp >> 7;
    const int w0 = lp & 127;          // multiple of 4

    // hoist stamp load: latency overlaps the shuffle preamble
    const f32x4 sv = *reinterpret_cast<const f32x4*>(stamp + h * 128 + w0);

    // ---- barrier-free preamble: per-wave redundant, all via shuffles ----
    const float v = inputs[b * 32 + (lane & 31)];   // lanes 32..63 duplicate
    int bt = (int)rintf(v * 128.0f);                // round-half-even = np.round
    bt = bt < 0 ? 0 : (bt > 128 ? 128 : bt);        // per-lane bar height
    float mn = v, mx = v;
#pragma unroll
    for (int off = 1; off < 32; off <<= 1) {        // within-half butterfly
        mn = fminf(mn, __shfl_xor(mn, off));
        mx = fmaxf(mx, __shfl_xor(mx, off));
    }
    const float inv = 1.0f / (mx - mn);             // dm min = 0 (diagonal)

    const float rowv = __shfl(v, h >> 2);
    const float ndv = fabsf(rowv - __shfl(v, w0 >> 2)) * inv;

    alignas(16) float vals[20];
#pragma unroll
    for (int j = 0; j < 4; ++j) {
        const int w = w0 + j;
        const int t = w - 17;
        const int bar = t / 3;
        const bool valid = (t >= 0) && (t <= 93) && (t - bar * 3 == 0);
        const int bhv = __shfl(bt, valid ? bar : 0);
        vals[5 * j + 0] = sv[j];
        vals[5 * j + 1] = 0.0f;                     // ch1 patched below
        vals[5 * j + 2] = rowv;
        vals[5 * j + 3] = ndv;
        vals[5 * j + 4] = (valid && h < bhv) ? 1.0f : 0.0f;
    }

    // stage: 5 x ds_write_b128 (80B/thread; odd f4 stride = baseline banking)
    f32x4* lw = reinterpret_cast<f32x4*>(&buf[tid * 20]);
    const f32x4* src = reinterpret_cast<const f32x4*>(vals);
#pragma unroll
    for (int k = 0; k < 5; ++k) lw[k] = src[k];
    __syncthreads();

    // ---- fused scatter: patch staged tile; coord d lands here iff r>>3==part
    if (tid < 32) {
        const int r = coords[2 * tid], c = coords[2 * tid + 1];
        if ((r >> 3) == part)
            atomicAdd(&buf[((r & 7) * 128 + c) * 5 + 1], __shfl(v, tid));
    }
    __syncthreads();

    // ---- flush: 5 back-to-back nontemporal dwordx4; wave = contiguous 1024B
    f32x4* dst = reinterpret_cast<f32x4*>(out) +
                 (size_t)b * 20480 + (size_t)part * 1280;
    const f32x4* lr = reinterpret_cast<const f32x4*>(buf);
#pragma unroll
    for (int it = 0; it < 5; ++it) {
        const int f = it * 256 + tid;
        __builtin_nontemporal_store(lr[f], dst + f);
    }
}

extern "C" void kernel_launch(void* const* d_in, const int* in_sizes, int n_in,
                              void* d_out, int out_size, void* d_ws, size_t ws_size,
                              hipStream_t stream) {
    const float* inputs = (const float*)d_in[0];   // [512,32]
    const float* stamp  = (const float*)d_in[1];   // [128,128,1]
    const int*   coords = (const int*)d_in[2];     // [32,2]
    float* out = (float*)d_out;                    // [512,128,128,5]

    di_main<<<8192, 256, 0, stream>>>(inputs, stamp, coords, out);
}

// Round 9
// 167.339 us; speedup vs baseline: 1.0323x; 1.0323x over previous
//
#include <hip/hip_runtime.h>

// Output: (B=512, H=128, W=128, C=5) fp32.
// ch0 = stamp[h,w]; ch1 = scatter-add (fused via LDS patch); ch2 = x[b,h>>2];
// ch3 = |x[b,h>>2]-x[b,w>>2]| / (max-min); ch4 = bar (col 17+3i is bar i, h<bh[i]).
// Block = (b, part): 1024 pixels = rows [part*8, part*8+8) of image b.
// compute -> stage(LDS) -> barrier -> patch ch1 (LDS atomics) -> barrier ->
// 5 back-to-back dwordx4 stores (wave = contiguous 1024B). No post-store
// barrier, no global atomics: waves retire as soon as stores issue.

typedef float f32x4 __attribute__((ext_vector_type(4)));

__global__ __launch_bounds__(256) void di_main(const float* __restrict__ inputs,
                                               const float* __restrict__ stamp,
                                               const int* __restrict__ coords,
                                               float* __restrict__ out) {
    const int blk = blockIdx.x;     // 8192 blocks: 512 b x 16 parts
    const int b = blk >> 4;
    const int part = blk & 15;
    const int tid = threadIdx.x;
    const int lane = tid & 63;

    __shared__ float buf[256 * 20];   // 20 KB staging -> 8 blocks/CU

    // pixel span: lp..lp+3 (one row-quarter of 4 px)
    const int lp = part * 1024 + tid * 4;
    const int h = lp >> 7;
    const int w0 = lp & 127;          // multiple of 4

    // hoist stamp load: latency overlaps the shuffle preamble
    const f32x4 sv = *reinterpret_cast<const f32x4*>(stamp + h * 128 + w0);

    // ---- barrier-free preamble: per-wave redundant, all via shuffles ----
    const float v = inputs[b * 32 + (lane & 31)];   // lanes 32..63 duplicate
    int bt = (int)rintf(v * 128.0f);                // round-half-even = np.round
    bt = bt < 0 ? 0 : (bt > 128 ? 128 : bt);        // per-lane bar height
    float mn = v, mx = v;
#pragma unroll
    for (int off = 1; off < 32; off <<= 1) {        // within-half butterfly
        mn = fminf(mn, __shfl_xor(mn, off));
        mx = fmaxf(mx, __shfl_xor(mx, off));
    }
    const float inv = 1.0f / (mx - mn);             // dm min = 0 (diagonal)

    const float rowv = __shfl(v, h >> 2);
    const float ndv = fabsf(rowv - __shfl(v, w0 >> 2)) * inv;

    alignas(16) float vals[20];
#pragma unroll
    for (int j = 0; j < 4; ++j) {
        const int w = w0 + j;
        const int t = w - 17;
        const int bar = t / 3;
        const bool valid = (t >= 0) && (t <= 93) && (t - bar * 3 == 0);
        const int bhv = __shfl(bt, valid ? bar : 0);
        vals[5 * j + 0] = sv[j];
        vals[5 * j + 1] = 0.0f;                     // ch1 patched below
        vals[5 * j + 2] = rowv;
        vals[5 * j + 3] = ndv;
        vals[5 * j + 4] = (valid && h < bhv) ? 1.0f : 0.0f;
    }

    // stage: 5 x ds_write_b128 (80B/thread; odd f4 stride = baseline banking)
    f32x4* lw = reinterpret_cast<f32x4*>(&buf[tid * 20]);
    const f32x4* src = reinterpret_cast<const f32x4*>(vals);
#pragma unroll
    for (int k = 0; k < 5; ++k) lw[k] = src[k];
    __syncthreads();

    // ---- fused scatter: patch staged tile; coord d lands here iff r>>3==part
    if (tid < 32) {
        const int r = coords[2 * tid], c = coords[2 * tid + 1];
        if ((r >> 3) == part)
            atomicAdd(&buf[((r & 7) * 128 + c) * 5 + 1], __shfl(v, tid));
    }
    __syncthreads();

    // ---- flush: 5 back-to-back dwordx4; each wave store = contiguous 1024B
    f32x4* dst = reinterpret_cast<f32x4*>(out) +
                 (size_t)b * 20480 + (size_t)part * 1280;
    const f32x4* lr = reinterpret_cast<const f32x4*>(buf);
#pragma unroll
    for (int it = 0; it < 5; ++it) {
        const int f = it * 256 + tid;
        dst[f] = lr[f];
    }
}

extern "C" void kernel_launch(void* const* d_in, const int* in_sizes, int n_in,
                              void* d_out, int out_size, void* d_ws, size_t ws_size,
                              hipStream_t stream) {
    const float* inputs = (const float*)d_in[0];   // [512,32]
    const float* stamp  = (const float*)d_in[1];   // [128,128,1]
    const int*   coords = (const int*)d_in[2];     // [32,2]
    float* out = (float*)d_out;                    // [512,128,128,5]

    di_main<<<8192, 256, 0, stream>>>(inputs, stamp, coords, out);
}